// Round 16
// baseline (182.513 us; speedup 1.0000x reference)
//
#include <hip/hip_runtime.h>
#include <hip/hip_bf16.h>

#define NROWS 8192
#define DDIM  512
#define NS    64
#define KK    8
#define HH    240
#define SP2   72     // samp pitch, f16 elems (64 + 8 pad)
#define RGN   2048   // one 64x32 f16 region, ushorts
#define STG   6144   // stage = A_X | A_Y | B regions

typedef __attribute__((ext_vector_type(8))) _Float16 f16x8;
typedef __attribute__((ext_vector_type(4))) _Float16 f16x4;
typedef __attribute__((ext_vector_type(4))) float f32x4;
typedef __attribute__((ext_vector_type(2))) float f32x2;

typedef __attribute__((address_space(3))) void       lds_void;
typedef const __attribute__((address_space(1))) void gbl_cvoid;

__device__ inline unsigned pk2u(float a, float b) {
    auto h = __builtin_amdgcn_cvt_pkrtz(a, b);
    unsigned u;
    __builtin_memcpy(&u, &h, sizeof(u));
    return u;
}

__device__ inline void gl16(const ushort* g, ushort* l) {
    __builtin_amdgcn_global_load_lds((gbl_cvoid*)g, (lds_void*)l, 16, 0, 0);
}

// ---------------------------------------------------------------------------
// Kernel 0: pack X, Y, Th, W1 to f16.
// ---------------------------------------------------------------------------
#define XN (NROWS * DDIM)          // 4194304
__global__ __launch_bounds__(256)
void pack_kernel(const float* __restrict__ X, const float* __restrict__ Y,
                 const float* __restrict__ Th, const float* __restrict__ W1,
                 ushort* __restrict__ Xh, ushort* __restrict__ Yh,
                 ushort* __restrict__ Thh, ushort* __restrict__ W1h)
{
    int i = (blockIdx.x * 256 + threadIdx.x) * 4;
    const float* src; ushort* dst; int off;
    if (i < XN)               { src = X;  dst = Xh;  off = i; }
    else if (i < 2 * XN)      { src = Y;  dst = Yh;  off = i - XN; }
    else if (i < 2 * XN + 262144) { src = Th; dst = Thh; off = i - 2 * XN; }
    else                      { src = W1; dst = W1h; off = i - (2 * XN + 262144); }
    float4 v = *(const float4*)(src + off);
    *(uint2*)(dst + off) = make_uint2(pk2u(v.x, v.y), pk2u(v.z, v.w));
}

// ---------------------------------------------------------------------------
// Main fused kernel — X and Y FUSED per block (r16):
//  phase 1: sampX, sampY (64x64 each) = {Xh,Yh} @ Thh^T with SHARED B staging.
//           BK=32, gl16 (zero staging VGPRs, r15), LDS dbuf, 1 barrier/step,
//           8 MFMA/step (2x r15's per-barrier matrix work). Both-sides XOR
//           swizzle -> 0 bank conflicts (r15-verified).
//  phase 2: accX/accY (+noise on X) -> f16 samp LDS [128][SP2]
//  phase 3: layer-1 mfma_f32_16x16x16f16; W1-frag/b1/w3 loaded ONCE for both
//           X and Y (weight traffic halved); fused row reductions.
// grid = (128, 8); block = 256 (4 waves, 2x2 over 64x64).
// acc 32 AGPR + ~64 arch VGPR: r4 precedent (52+64) says no spill at (256,4).
// ---------------------------------------------------------------------------
__global__ __launch_bounds__(256, 4)
void proj_mlp_kernel(const ushort* __restrict__ Xh,
                     const ushort* __restrict__ Yh,
                     const float* __restrict__ Xn,
                     const ushort* __restrict__ Thh,
                     const ushort* __restrict__ W1h,
                     const float* __restrict__ b1,
                     const float* __restrict__ W3,
                     const float* __restrict__ sig_p,
                     float* __restrict__ sumx,   // [NS][128]
                     float* __restrict__ maxy,   // [NS][128]
                     float* __restrict__ sey)    // [NS][128]
{
    __shared__ __align__(16) ushort smem[2 * STG];   // 24576 B
    ushort* sl = smem;                               // samp [128][SP2] (reuse)

    const int tid  = threadIdx.x;
    const int w    = __builtin_amdgcn_readfirstlane(tid >> 6);
    const int lane = tid & 63;
    const int bxl  = blockIdx.x;      // 0..127 row tile (both X and Y)
    const int by   = blockIdx.y;      // 8-slice group

    // gl16 lane mapping (r15): wave w covers rows 16w..16w+15 of each region
    const int grow = (w << 4) + (lane >> 2);
    const int gchk = (lane & 3) ^ ((grow >> 1) & 3);
    const ushort* gAX = Xh + (size_t)(bxl * 64 + grow) * DDIM + gchk * 8;
    const ushort* gAY = Yh + (size_t)(bxl * 64 + grow) * DDIM + gchk * 8;
    const ushort* gB  = Thh + (size_t)(by * 64 + grow) * DDIM + gchk * 8;
    const int woff = w * 512;

    f32x4 accX[2][2], accY[2][2];
#pragma unroll
    for (int m = 0; m < 2; ++m)
#pragma unroll
        for (int n = 0; n < 2; ++n) {
            accX[m][n] = (f32x4){0.f, 0.f, 0.f, 0.f};
            accY[m][n] = (f32x4){0.f, 0.f, 0.f, 0.f};
        }

    const int wr  = (w >> 1) * 32;
    const int wc  = (w & 1) * 32;
    const int r16 = lane & 15;
    const int hi4 = lane >> 4;

    int offA[2], offB[2];
#pragma unroll
    for (int m = 0; m < 2; ++m) {
        int row = wr + m * 16 + r16;
        offA[m] = row * 32 + ((hi4 ^ ((row >> 1) & 3)) * 8);
    }
#pragma unroll
    for (int n = 0; n < 2; ++n) {
        int row = wc + n * 16 + r16;
        offB[n] = 2 * RGN + row * 32 + ((hi4 ^ ((row >> 1) & 3)) * 8);
    }

    // prologue: tile 0 -> stage 0
    gl16(gAX, &smem[woff]);
    gl16(gAY, &smem[RGN + woff]);
    gl16(gB,  &smem[2 * RGN + woff]);
    __syncthreads();

#pragma unroll
    for (int kt = 0; kt < 16; ++kt) {
        const int cur = (kt & 1) * STG;
        if (kt < 15) {                       // issue t+1 into other stage
            const int nxt = STG - cur;
            const int k1 = (kt + 1) * 32;
            gl16(gAX + k1, &smem[nxt + woff]);
            gl16(gAY + k1, &smem[nxt + RGN + woff]);
            gl16(gB  + k1, &smem[nxt + 2 * RGN + woff]);
        }
        f16x8 bfv[2], ax[2], ay[2];
#pragma unroll
        for (int n = 0; n < 2; ++n) bfv[n] = *(const f16x8*)(smem + cur + offB[n]);
#pragma unroll
        for (int m = 0; m < 2; ++m) {
            ax[m] = *(const f16x8*)(smem + cur + offA[m]);
            ay[m] = *(const f16x8*)(smem + cur + RGN + offA[m]);
        }
#pragma unroll
        for (int m = 0; m < 2; ++m)
#pragma unroll
            for (int n = 0; n < 2; ++n) {
                accX[m][n] = __builtin_amdgcn_mfma_f32_16x16x32_f16(
                    ax[m], bfv[n], accX[m][n], 0, 0, 0);
                accY[m][n] = __builtin_amdgcn_mfma_f32_16x16x32_f16(
                    ay[m], bfv[n], accY[m][n], 0, 0, 0);
            }
        __syncthreads();
    }

    // ---- phase 2: accX/accY (+noise on X) -> f16 samp LDS [128][SP2] --------
    const float sig = *sig_p;
    const bool addnoise = (sig > 0.f);
    const int n0g = bxl * 64;

#pragma unroll
    for (int m = 0; m < 2; ++m)
#pragma unroll
        for (int n = 0; n < 2; ++n) {
            const int col  = wc + n * 16 + r16;
            const int rowb = wr + m * 16 + hi4 * 4;
            float vx[4], vy[4];
#pragma unroll
            for (int j = 0; j < 4; ++j) {
                vx[j] = accX[m][n][j];
                if (addnoise)
                    vx[j] = fmaf(sig, Xn[(size_t)(n0g + rowb + j) * (NS * KK) + by * 64 + col], vx[j]);
                vy[j] = accY[m][n][j];
            }
            unsigned x01 = pk2u(vx[0], vx[1]), x23 = pk2u(vx[2], vx[3]);
            unsigned y01 = pk2u(vy[0], vy[1]), y23 = pk2u(vy[2], vy[3]);
            sl[(rowb + 0) * SP2 + col] = (ushort)x01;
            sl[(rowb + 1) * SP2 + col] = (ushort)(x01 >> 16);
            sl[(rowb + 2) * SP2 + col] = (ushort)x23;
            sl[(rowb + 3) * SP2 + col] = (ushort)(x23 >> 16);
            sl[(64 + rowb + 0) * SP2 + col] = (ushort)y01;
            sl[(64 + rowb + 1) * SP2 + col] = (ushort)(y01 >> 16);
            sl[(64 + rowb + 2) * SP2 + col] = (ushort)y23;
            sl[(64 + rowb + 3) * SP2 + col] = (ushort)(y23 >> 16);
        }
    __syncthreads();

    // ---- phase 3: layer-1 MFMA, weights shared across X and Y ---------------
#pragma unroll 1
    for (int si = 0; si < 2; ++si) {
        const int sloc = w * 2 + si;
        const int s    = by * 8 + sloc;

        f16x4 bsx[4], bsy[4];
#pragma unroll
        for (int nt = 0; nt < 4; ++nt) {
            f16x4 tx = {0, 0, 0, 0}, ty = {0, 0, 0, 0};
            if (hi4 < 2) {
                tx = *(const f16x4*)(sl + (nt * 16 + r16) * SP2 + sloc * 8 + hi4 * 4);
                ty = *(const f16x4*)(sl + (64 + nt * 16 + r16) * SP2 + sloc * 8 + hi4 * 4);
            }
            bsx[nt] = tx; bsy[nt] = ty;
        }

        const ushort* w1p = W1h + (size_t)s * HH * KK;
        const float*  b1p = b1 + s * HH;
        const float*  w3p = W3 + s * HH;

        f32x2 px2[4], py2[4];
#pragma unroll
        for (int nt = 0; nt < 4; ++nt) {
            px2[nt] = (f32x2){0.f, 0.f};
            py2[nt] = (f32x2){0.f, 0.f};
        }

#pragma unroll 5
        for (int ht = 0; ht < HH / 16; ++ht) {
            f16x4 aw = {0, 0, 0, 0};
            if (hi4 < 2)
                aw = *(const f16x4*)(w1p + (ht * 16 + r16) * 8 + hi4 * 4);
            float4 b4 = *(const float4*)(b1p + ht * 16 + hi4 * 4);
            float4 w4 = *(const float4*)(w3p + ht * 16 + hi4 * 4);
            f32x4 z   = (f32x4){b4.x, b4.y, b4.z, b4.w};
            f32x2 w01 = (f32x2){w4.x, w4.y};
            f32x2 w23 = (f32x2){w4.z, w4.w};
            const f32x2 zero2 = (f32x2){0.f, 0.f};
#pragma unroll
            for (int nt = 0; nt < 4; ++nt) {
                f32x4 tx = __builtin_amdgcn_mfma_f32_16x16x16f16(aw, bsx[nt], z, 0, 0, 0);
                f32x4 ty = __builtin_amdgcn_mfma_f32_16x16x16f16(aw, bsy[nt], z, 0, 0, 0);
                f32x2 a01 = (f32x2){tx[0], tx[1]}, a23 = (f32x2){tx[2], tx[3]};
                f32x2 c01 = (f32x2){ty[0], ty[1]}, c23 = (f32x2){ty[2], ty[3]};
                a01 = __builtin_elementwise_max(a01, zero2);
                a23 = __builtin_elementwise_max(a23, zero2);
                c01 = __builtin_elementwise_max(c01, zero2);
                c23 = __builtin_elementwise_max(c23, zero2);
                px2[nt] = __builtin_elementwise_fma(a01, w01, px2[nt]);
                px2[nt] = __builtin_elementwise_fma(a23, w23, px2[nt]);
                py2[nt] = __builtin_elementwise_fma(c01, w01, py2[nt]);
                py2[nt] = __builtin_elementwise_fma(c23, w23, py2[nt]);
            }
        }

        // X: total sum over 64 rows
        float lsum = 0.f;
#pragma unroll
        for (int nt = 0; nt < 4; ++nt) lsum += px2[nt].x + px2[nt].y;
#pragma unroll
        for (int off = 1; off < 64; off <<= 1)
            lsum += __shfl_xor(lsum, off);
        if (lane == 0) sumx[s * 128 + bxl] = lsum;

        // Y: per-row preds -> online max/expsum over 64 rows
        float p[4];
#pragma unroll
        for (int nt = 0; nt < 4; ++nt) {
            f32x2 v = py2[nt];
            v.x += __shfl_xor(v.x, 16);
            v.y += __shfl_xor(v.y, 16);
            v.x += __shfl_xor(v.x, 32);
            v.y += __shfl_xor(v.y, 32);
            p[nt] = v.x + v.y;
        }
        float M = fmaxf(fmaxf(p[0], p[1]), fmaxf(p[2], p[3]));
        float se = __expf(p[0] - M) + __expf(p[1] - M)
                 + __expf(p[2] - M) + __expf(p[3] - M);
#pragma unroll
        for (int off = 1; off < 16; off <<= 1) {
            float Mo = __shfl_xor(M, off);
            float so = __shfl_xor(se, off);
            float Mm = fmaxf(M, Mo);
            se = se * __expf(M - Mm) + so * __expf(Mo - Mm);
            M = Mm;
        }
        if (lane == 0) {
            maxy[s * 128 + bxl] = M;
            sey[s * 128 + bxl]  = se;
        }
    }
}

// ---------------------------------------------------------------------------
// Final: 256 threads; thread (s, q) covers 32 partials; shfl-combine; wave-0
// reduces 64 slice terms -> scalar.
// ---------------------------------------------------------------------------
__global__ __launch_bounds__(256)
void final_kernel(const float* __restrict__ sumx,
                  const float* __restrict__ maxy,
                  const float* __restrict__ sey,
                  float* __restrict__ out)
{
    __shared__ float term_s[NS];
    const int tid = threadIdx.x;
    const int s = tid >> 2, q = tid & 3;
    const int base = s * 128 + q * 32;

    float sum = 0.f, M = -3.4e38f;
#pragma unroll 8
    for (int i = 0; i < 32; ++i) {
        sum += sumx[base + i];
        M = fmaxf(M, maxy[base + i]);
    }
    float se = 0.f;
#pragma unroll 8
    for (int i = 0; i < 32; ++i)
        se += sey[base + i] * __expf(maxy[base + i] - M);

#pragma unroll
    for (int off = 1; off < 4; off <<= 1) {
        float Mo = __shfl_xor(M, off);
        float so = __shfl_xor(se, off);
        float su = __shfl_xor(sum, off);
        float Mm = fmaxf(M, Mo);
        se = se * __expf(M - Mm) + so * __expf(Mo - Mm);
        M = Mm;
        sum += su;
    }
    if (q == 0)
        term_s[s] = M + logf(se) - logf((float)NROWS) - sum * (1.0f / (float)NROWS);
    __syncthreads();
    if (tid < 64) {
        float v = term_s[tid];
#pragma unroll
        for (int off = 1; off < 64; off <<= 1) v += __shfl_xor(v, off);
        if (tid == 0) out[0] = v * (1.0f / (float)NS);
    }
}

// ---------------------------------------------------------------------------
extern "C" void kernel_launch(void* const* d_in, const int* in_sizes, int n_in,
                              void* d_out, int out_size, void* d_ws, size_t ws_size,
                              hipStream_t stream)
{
    const float* X   = (const float*)d_in[0];
    const float* Y   = (const float*)d_in[1];
    const float* Xn  = (const float*)d_in[2];
    const float* Th  = (const float*)d_in[3];
    const float* W1  = (const float*)d_in[4];
    const float* b1  = (const float*)d_in[5];
    const float* W3  = (const float*)d_in[6];
    // d_in[7] = b3: cancels exactly between mean_x and LSE_y -> unused
    const float* sig = (const float*)d_in[8];

    ushort* Xh   = (ushort*)d_ws;                     // 4,194,304 f16
    ushort* Yh   = Xh + XN;                           // 4,194,304 f16
    ushort* Thh  = Yh + XN;                           // 262,144 f16
    ushort* W1h  = Thh + 262144;                      // 122,880 f16
    float*  sumx = (float*)(W1h + 122880);
    float*  maxy = sumx + NS * 128;
    float*  sey  = maxy + NS * 128;

    pack_kernel<<<(2 * XN + 262144 + 122880) / 1024, 256, 0, stream>>>(
        X, Y, Th, W1, Xh, Yh, Thh, W1h);

    dim3 g1(128, 8, 1);
    proj_mlp_kernel<<<g1, 256, 0, stream>>>(Xh, Yh, Xn, Thh, W1h, b1, W3,
                                            sig, sumx, maxy, sey);
    final_kernel<<<1, 256, 0, stream>>>(sumx, maxy, sey, (float*)d_out);
}

// Round 17
// 65.267 us; speedup vs baseline: 2.7964x; 2.7964x over previous
//
#include <hip/hip_runtime.h>
#include <hip/hip_bf16.h>

#define NROWS 8192
#define DDIM  512
#define NS    64
#define KK    8
#define HH    240
#define SP2   72     // samp pitch, f16 elems (64 + 8 pad)
#define STG   4096   // one stage (A 2048 | B 2048 ushorts) = 8 KB

typedef __attribute__((ext_vector_type(8))) _Float16 f16x8;
typedef __attribute__((ext_vector_type(4))) _Float16 f16x4;
typedef __attribute__((ext_vector_type(4))) float f32x4;
typedef __attribute__((ext_vector_type(2))) float f32x2;

typedef __attribute__((address_space(3))) void       lds_void;
typedef const __attribute__((address_space(1))) void gbl_cvoid;

__device__ inline unsigned pk2u(float a, float b) {
    auto h = __builtin_amdgcn_cvt_pkrtz(a, b);
    unsigned u;
    __builtin_memcpy(&u, &h, sizeof(u));
    return u;
}

__device__ inline void gl16(const ushort* g, ushort* l) {
    __builtin_amdgcn_global_load_lds((gbl_cvoid*)g, (lds_void*)l, 16, 0, 0);
}

// ---------------------------------------------------------------------------
// Kernel 0: pack X, Y, Th, W1 to f16.
// ---------------------------------------------------------------------------
#define XN (NROWS * DDIM)          // 4194304
__global__ __launch_bounds__(256)
void pack_kernel(const float* __restrict__ X, const float* __restrict__ Y,
                 const float* __restrict__ Th, const float* __restrict__ W1,
                 ushort* __restrict__ Xh, ushort* __restrict__ Yh,
                 ushort* __restrict__ Thh, ushort* __restrict__ W1h)
{
    int i = (blockIdx.x * 256 + threadIdx.x) * 4;
    const float* src; ushort* dst; int off;
    if (i < XN)               { src = X;  dst = Xh;  off = i; }
    else if (i < 2 * XN)      { src = Y;  dst = Yh;  off = i - XN; }
    else if (i < 2 * XN + 262144) { src = Th; dst = Thh; off = i - 2 * XN; }
    else                      { src = W1; dst = W1h; off = i - (2 * XN + 262144); }
    float4 v = *(const float4*)(src + off);
    *(uint2*)(dst + off) = make_uint2(pk2u(v.x, v.y), pk2u(v.z, v.w));
}

// ---------------------------------------------------------------------------
// Main fused kernel (f16 operands, fp32 accumulate) — r15 + T4 counted vmcnt:
//  phase 1: samp64x64 = Ah @ Thh^T. BK=32, gl16 staging (zero staging VGPRs,
//           r15-proven), 3-stage LDS pipeline, depth-2 prefetch, per-step
//           raw {s_waitcnt vmcnt(2); s_barrier} — loads stay in flight
//           across barriers (never drain to 0 in the loop). r15's
//           __syncthreads drained vmcnt(0) every step -> ~250 cyc exposed
//           latency x16 steps; this removes it.
//  phase 2: acc (+noise) -> f16 samp LDS [64][SP2]
//  phase 3: layer-1 mfma_f32_16x16x16f16, b1 in C-init, relu + packed-W3
//           fma, fused row reductions. Unchanged from r15.
// grid = (256, 8); block = 256 (4 waves, 2x2 over 64x64). LDS 24 KB.
// 64-VGPR law (r8-r16): no new live registers vs r15.
// ---------------------------------------------------------------------------
__global__ __launch_bounds__(256, 4)
void proj_mlp_kernel(const ushort* __restrict__ Xh,
                     const ushort* __restrict__ Yh,
                     const float* __restrict__ Xn,
                     const ushort* __restrict__ Thh,
                     const ushort* __restrict__ W1h,
                     const float* __restrict__ b1,
                     const float* __restrict__ W3,
                     const float* __restrict__ sig_p,
                     float* __restrict__ sumx,   // [NS][128]
                     float* __restrict__ maxy,   // [NS][128]
                     float* __restrict__ sey)    // [NS][128]
{
    __shared__ __align__(16) ushort smem[3 * STG];   // 24576 B
    ushort* sl = smem;                               // samp [64][SP2] (reuse)

    const int tid  = threadIdx.x;
    const int w    = __builtin_amdgcn_readfirstlane(tid >> 6);
    const int lane = tid & 63;
    const int bx   = blockIdx.x;
    const int by   = blockIdx.y;

    const bool isX = (bx < 128);
    const int  bxl = isX ? bx : (bx - 128);
    const ushort* srcA = (isX ? Xh : Yh) + (size_t)bxl * 64 * DDIM;

    // gl16 lane mapping: wave w covers rows 16w..16w+15; chunk XOR-swizzled
    const int grow = (w << 4) + (lane >> 2);
    const int gchk = (lane & 3) ^ ((grow >> 1) & 3);
    const ushort* gA = srcA + (size_t)grow * DDIM + gchk * 8;
    const ushort* gB = Thh + (size_t)(by * 64 + grow) * DDIM + gchk * 8;
    const int woff = w * 512;

    f32x4 acc[2][2];
#pragma unroll
    for (int m = 0; m < 2; ++m)
#pragma unroll
        for (int n = 0; n < 2; ++n) acc[m][n] = (f32x4){0.f, 0.f, 0.f, 0.f};

    const int wr  = (w >> 1) * 32;
    const int wc  = (w & 1) * 32;
    const int r16 = lane & 15;
    const int hi4 = lane >> 4;

    int offA[2], offB[2];
#pragma unroll
    for (int m = 0; m < 2; ++m) {
        int row = wr + m * 16 + r16;
        offA[m] = row * 32 + ((hi4 ^ ((row >> 1) & 3)) * 8);
    }
#pragma unroll
    for (int n = 0; n < 2; ++n) {
        int row = wc + n * 16 + r16;
        offB[n] = 2048 + row * 32 + ((hi4 ^ ((row >> 1) & 3)) * 8);
    }

    // prologue: issue tiles 0 and 1 (no wait)
    gl16(gA,      &smem[woff]);
    gl16(gB,      &smem[2048 + woff]);
    gl16(gA + 32, &smem[STG + woff]);
    gl16(gB + 32, &smem[STG + 2048 + woff]);

#pragma unroll
    for (int kt = 0; kt < 16; ++kt) {
        // wait MY pair-kt (leave later pairs in flight), then publish via barrier
        if (kt < 15)
            asm volatile("s_waitcnt vmcnt(2)\n\ts_barrier" ::: "memory");
        else
            asm volatile("s_waitcnt vmcnt(0)\n\ts_barrier" ::: "memory");

        // issue pair kt+2 into stage (kt+2)%3 (read kt-1, all waves past it)
        if (kt < 14) {
            const int st = ((kt + 2) % 3) * STG;
            gl16(gA + (kt + 2) * 32, &smem[st + woff]);
            gl16(gB + (kt + 2) * 32, &smem[st + 2048 + woff]);
        }

        const int cur = (kt % 3) * STG;
        f16x8 af[2], bfv[2];
#pragma unroll
        for (int m = 0; m < 2; ++m) af[m]  = *(const f16x8*)(smem + cur + offA[m]);
#pragma unroll
        for (int n = 0; n < 2; ++n) bfv[n] = *(const f16x8*)(smem + cur + offB[n]);
#pragma unroll
        for (int m = 0; m < 2; ++m)
#pragma unroll
            for (int n = 0; n < 2; ++n)
                acc[m][n] = __builtin_amdgcn_mfma_f32_16x16x32_f16(
                    af[m], bfv[n], acc[m][n], 0, 0, 0);
    }
    __syncthreads();   // all waves done reading stages before samp aliases them

    // ---- phase 2: acc (+noise) -> f16 samp LDS ------------------------------
    const float sig = *sig_p;
    const bool addnoise = (sig > 0.f) && isX;
    const int n0g = bxl * 64;

#pragma unroll
    for (int m = 0; m < 2; ++m)
#pragma unroll
        for (int n = 0; n < 2; ++n) {
            const int col  = wc + n * 16 + r16;
            const int rowb = wr + m * 16 + hi4 * 4;
            float v[4];
#pragma unroll
            for (int j = 0; j < 4; ++j) {
                v[j] = acc[m][n][j];
                if (addnoise)
                    v[j] = fmaf(sig, Xn[(size_t)(n0g + rowb + j) * (NS * KK) + by * 64 + col], v[j]);
            }
            unsigned u01 = pk2u(v[0], v[1]);
            unsigned u23 = pk2u(v[2], v[3]);
            sl[(rowb + 0) * SP2 + col] = (ushort)u01;
            sl[(rowb + 1) * SP2 + col] = (ushort)(u01 >> 16);
            sl[(rowb + 2) * SP2 + col] = (ushort)u23;
            sl[(rowb + 3) * SP2 + col] = (ushort)(u23 >> 16);
        }
    __syncthreads();

    // ---- phase 3: layer-1 16x16x16 f16 MFMA + fused reductions --------------
#pragma unroll 1
    for (int si = 0; si < 2; ++si) {
        const int sloc = w * 2 + si;
        const int s    = by * 8 + sloc;

        f16x4 bsamp[4];
#pragma unroll
        for (int nt = 0; nt < 4; ++nt) {
            f16x4 t = {0, 0, 0, 0};
            if (hi4 < 2)
                t = *(const f16x4*)(sl + (nt * 16 + r16) * SP2 + sloc * 8 + hi4 * 4);
            bsamp[nt] = t;
        }

        const ushort* w1p = W1h + (size_t)s * HH * KK;
        const float*  b1p = b1 + s * HH;
        const float*  w3p = W3 + s * HH;

        f32x2 pn2[4];
#pragma unroll
        for (int nt = 0; nt < 4; ++nt) pn2[nt] = (f32x2){0.f, 0.f};

#pragma unroll 5
        for (int ht = 0; ht < HH / 16; ++ht) {
            f16x4 aw = {0, 0, 0, 0};
            if (hi4 < 2)
                aw = *(const f16x4*)(w1p + (ht * 16 + r16) * 8 + hi4 * 4);
            float4 b4 = *(const float4*)(b1p + ht * 16 + hi4 * 4);
            float4 w4 = *(const float4*)(w3p + ht * 16 + hi4 * 4);
            f32x4 z   = (f32x4){b4.x, b4.y, b4.z, b4.w};
            f32x2 w01 = (f32x2){w4.x, w4.y};
            f32x2 w23 = (f32x2){w4.z, w4.w};
            const f32x2 zero2 = (f32x2){0.f, 0.f};
#pragma unroll
            for (int nt = 0; nt < 4; ++nt) {
                f32x4 t = __builtin_amdgcn_mfma_f32_16x16x16f16(aw, bsamp[nt], z, 0, 0, 0);
                f32x2 t01 = (f32x2){t[0], t[1]};
                f32x2 t23 = (f32x2){t[2], t[3]};
                t01 = __builtin_elementwise_max(t01, zero2);
                t23 = __builtin_elementwise_max(t23, zero2);
                pn2[nt] = __builtin_elementwise_fma(t01, w01, pn2[nt]);
                pn2[nt] = __builtin_elementwise_fma(t23, w23, pn2[nt]);
            }
        }

        if (isX) {
            float lsum = 0.f;
#pragma unroll
            for (int nt = 0; nt < 4; ++nt) lsum += pn2[nt].x + pn2[nt].y;
#pragma unroll
            for (int off = 1; off < 64; off <<= 1)
                lsum += __shfl_xor(lsum, off);
            if (lane == 0) sumx[s * 128 + bxl] = lsum;
        } else {
            float p[4];
#pragma unroll
            for (int nt = 0; nt < 4; ++nt) {
                f32x2 v = pn2[nt];
                v.x += __shfl_xor(v.x, 16);
                v.y += __shfl_xor(v.y, 16);
                v.x += __shfl_xor(v.x, 32);
                v.y += __shfl_xor(v.y, 32);
                p[nt] = v.x + v.y;
            }
            float M = fmaxf(fmaxf(p[0], p[1]), fmaxf(p[2], p[3]));
            float se = __expf(p[0] - M) + __expf(p[1] - M)
                     + __expf(p[2] - M) + __expf(p[3] - M);
#pragma unroll
            for (int off = 1; off < 16; off <<= 1) {
                float Mo = __shfl_xor(M, off);
                float so = __shfl_xor(se, off);
                float Mm = fmaxf(M, Mo);
                se = se * __expf(M - Mm) + so * __expf(Mo - Mm);
                M = Mm;
            }
            if (lane == 0) {
                maxy[s * 128 + bxl] = M;
                sey[s * 128 + bxl]  = se;
            }
        }
    }
}

// ---------------------------------------------------------------------------
// Final: 256 threads; thread (s, q) covers 32 partials; shfl-combine; wave-0
// reduces 64 slice terms -> scalar.
// ---------------------------------------------------------------------------
__global__ __launch_bounds__(256)
void final_kernel(const float* __restrict__ sumx,
                  const float* __restrict__ maxy,
                  const float* __restrict__ sey,
                  float* __restrict__ out)
{
    __shared__ float term_s[NS];
    const int tid = threadIdx.x;
    const int s = tid >> 2, q = tid & 3;
    const int base = s * 128 + q * 32;

    float sum = 0.f, M = -3.4e38f;
#pragma unroll 8
    for (int i = 0; i < 32; ++i) {
        sum += sumx[base + i];
        M = fmaxf(M, maxy[base + i]);
    }
    float se = 0.f;
#pragma unroll 8
    for (int i = 0; i < 32; ++i)
        se += sey[base + i] * __expf(maxy[base + i] - M);

#pragma unroll
    for (int off = 1; off < 4; off <<= 1) {
        float Mo = __shfl_xor(M, off);
        float so = __shfl_xor(se, off);
        float su = __shfl_xor(sum, off);
        float Mm = fmaxf(M, Mo);
        se = se * __expf(M - Mm) + so * __expf(Mo - Mm);
        M = Mm;
        sum += su;
    }
    if (q == 0)
        term_s[s] = M + logf(se) - logf((float)NROWS) - sum * (1.0f / (float)NROWS);
    __syncthreads();
    if (tid < 64) {
        float v = term_s[tid];
#pragma unroll
        for (int off = 1; off < 64; off <<= 1) v += __shfl_xor(v, off);
        if (tid == 0) out[0] = v * (1.0f / (float)NS);
    }
}

// ---------------------------------------------------------------------------
extern "C" void kernel_launch(void* const* d_in, const int* in_sizes, int n_in,
                              void* d_out, int out_size, void* d_ws, size_t ws_size,
                              hipStream_t stream)
{
    const float* X   = (const float*)d_in[0];
    const float* Y   = (const float*)d_in[1];
    const float* Xn  = (const float*)d_in[2];
    const float* Th  = (const float*)d_in[3];
    const float* W1  = (const float*)d_in[4];
    const float* b1  = (const float*)d_in[5];
    const float* W3  = (const float*)d_in[6];
    // d_in[7] = b3: cancels exactly between mean_x and LSE_y -> unused
    const float* sig = (const float*)d_in[8];

    ushort* Xh   = (ushort*)d_ws;                     // 4,194,304 f16
    ushort* Yh   = Xh + XN;                           // 4,194,304 f16
    ushort* Thh  = Yh + XN;                           // 262,144 f16
    ushort* W1h  = Thh + 262144;                      // 122,880 f16
    float*  sumx = (float*)(W1h + 122880);
    float*  maxy = sumx + NS * 128;
    float*  sey  = maxy + NS * 128;

    pack_kernel<<<(2 * XN + 262144 + 122880) / 1024, 256, 0, stream>>>(
        X, Y, Th, W1, Xh, Yh, Thh, W1h);

    dim3 g1(256, 8, 1);
    proj_mlp_kernel<<<g1, 256, 0, stream>>>(Xh, Yh, Xn, Thh, W1h, b1, W3,
                                            sig, sumx, maxy, sey);
    final_kernel<<<1, 256, 0, stream>>>(sumx, maxy, sey, (float*)d_out);
}